// Round 10
// baseline (268.048 us; speedup 1.0000x reference)
//
#include <hip/hip_runtime.h>
#include <hip/hip_cooperative_groups.h>

namespace cg = cooperative_groups;

#define NFEAT 128
#define HID 16
#define NCLS 40
#define BSHIFT 7                 // 128 nodes per bucket
#define BNODES 128
#define CAP 2560                 // slab capacity per bucket (Poisson mean ~2046, 11 sigma)
#define NBUCK_MAX 800            // >= ceil(100000/128)=782
#define BIN_CHUNK 4096           // edges per bin unit
#define APAD 17                  // accum stride: lane's 8 atomics -> 8 distinct banks
#define ZPAD 41

#define SCALE1 262144.0f         // 2^18 — layer-1 message quantization
#define SCALE2 65536.0f          // 2^16 — layer-2 message quantization

typedef __attribute__((ext_vector_type(8))) short short8;   // 8 x bf16 (4 VGPRs)
typedef __attribute__((ext_vector_type(4))) float f32x4;

__device__ __forceinline__ unsigned bf16_rne(float f) {
    unsigned u = __float_as_uint(f);
    return (u + 0x7FFFu + ((u >> 16) & 1u)) >> 16;
}
__device__ __forceinline__ float bf_lo(unsigned u) { return __uint_as_float(u << 16); }
__device__ __forceinline__ float bf_hi(unsigned u) { return __uint_as_float(u & 0xFFFF0000u); }

// ================= cooperative mega-kernel: whole pipeline, one dispatch ======
// phase 0: zero cursors                       | grid.sync
// phase 1: bin units [0,nbin) + gemm units    | grid.sync
// phase 2: gather1 (h1b -> h2b)               | grid.sync
// phase 3: gather2 + W2 + log_softmax -> out
// 256 blocks x 512 threads, __launch_bounds__(512,2): VGPR<=256, LDS 38.7KB
// -> runtime-validated 1 block/CU co-residency.
__global__ __launch_bounds__(512, 2) void mega_kernel(
    const int* __restrict__ src, const int* __restrict__ dst,
    const float* __restrict__ ew, int* __restrict__ cursor,
    int2* __restrict__ slab, int E, int nbuck, int nbin,
    const float* __restrict__ x, const float* __restrict__ W1,
    unsigned short* __restrict__ h1b, unsigned short* __restrict__ h2b,
    const float* __restrict__ W2, float* __restrict__ out, int n)
{
    __shared__ int   hist[NBUCK_MAX];       // 3.2 KB
    __shared__ int   runbase[NBUCK_MAX];    // 3.2 KB
    __shared__ int   accum[BNODES * APAD];  // 8.7 KB
    __shared__ float w2s[HID * NCLS];       // 2.56 KB
    __shared__ float zbuf[BNODES * ZPAD];   // 21 KB

    cg::grid_group grid = cg::this_grid();
    const int tid = threadIdx.x;
    const int bid = blockIdx.x;
    const int G   = gridDim.x;

    // ---------------- phase 0: zero cursors ----------------
    for (int i = bid * 512 + tid; i < NBUCK_MAX; i += G * 512) cursor[i] = 0;
    grid.sync();

    // ---------------- phase 1: bin + gemm units ----------------
    int ngemm = (n + 127) >> 7;              // 128 rows per gemm unit (8 waves x 16)
    int nunits = nbin + ngemm;
    for (int u = bid; u < nunits; u += G) {
        if (u < nbin) {
            // ----- bin unit: 4096 edges, 8 per thread -----
            for (int i = tid; i < NBUCK_MAX; i += 512) hist[i] = 0;
            __syncthreads();
            int base = u * BIN_CHUNK;
            int myd[8], mys[8], myw[8];
            #pragma unroll
            for (int k = 0; k < 8; ++k) {
                int e = base + k * 512 + tid;
                if (e < E) {
                    myd[k] = dst[e];
                    mys[k] = src[e];
                    myw[k] = __float_as_int(ew[e]);
                    atomicAdd(&hist[myd[k] >> BSHIFT], 1);
                } else myd[k] = -1;
            }
            __syncthreads();
            for (int i = tid; i < nbuck; i += 512) {
                int c = hist[i];
                runbase[i] = c ? (i * CAP + atomicAdd(&cursor[i], c)) : 0;
                hist[i] = 0;                 // reuse as intra-block rank cursor
            }
            __syncthreads();
            #pragma unroll
            for (int k = 0; k < 8; ++k) {
                int d = myd[k];
                if (d >= 0) {
                    int b = d >> BSHIFT;
                    int pos = runbase[b] + atomicAdd(&hist[b], 1);
                    if (pos < (b + 1) * CAP)             // overflow guard
                        slab[pos] = make_int2(mys[k] | ((d & (BNODES - 1)) << 20), myw[k]);
                }
            }
            __syncthreads();                 // protect hist before next unit re-zero
        } else {
            // ----- gemm unit: 128 rows via MFMA -----
            int wave = tid >> 6, lane = tid & 63;
            int m = lane & 15, q = lane >> 4;
            int rbase = (u - nbin) * 128 + wave * 16;

            short8 bfrag[4];
            #pragma unroll
            for (int kc = 0; kc < 4; ++kc) {
                #pragma unroll
                for (int j = 0; j < 8; ++j)
                    bfrag[kc][j] = (short)bf16_rne(W1[(kc * 32 + q * 8 + j) * HID + m]);
            }
            int rowa = rbase + m; if (rowa > n - 1) rowa = n - 1;
            const float* xr = x + (size_t)rowa * NFEAT;
            f32x4 acc = {0.f, 0.f, 0.f, 0.f};
            #pragma unroll
            for (int kc = 0; kc < 4; ++kc) {
                float4 a0 = *(const float4*)(xr + kc * 32 + q * 8);
                float4 a1 = *(const float4*)(xr + kc * 32 + q * 8 + 4);
                short8 af;
                af[0] = (short)bf16_rne(a0.x); af[1] = (short)bf16_rne(a0.y);
                af[2] = (short)bf16_rne(a0.z); af[3] = (short)bf16_rne(a0.w);
                af[4] = (short)bf16_rne(a1.x); af[5] = (short)bf16_rne(a1.y);
                af[6] = (short)bf16_rne(a1.z); af[7] = (short)bf16_rne(a1.w);
                acc = __builtin_amdgcn_mfma_f32_16x16x32_bf16(af, bfrag[kc], acc, 0, 0, 0);
            }
            #pragma unroll
            for (int reg = 0; reg < 4; ++reg) {
                int rowd = rbase + q * 4 + reg;
                if (rowd < n)
                    h1b[(size_t)rowd * HID + m] = (unsigned short)bf16_rne(acc[reg]);
            }
        }
    }
    grid.sync();

    // ---------------- phase 2: gather layer 1 (h1b -> h2b) ----------------
    {
        const uint4* hq = (const uint4*)h1b;
        uint4* outb = (uint4*)h2b;
        for (int b = bid; b < nbuck; b += G) {
            for (int i = tid; i < BNODES * APAD; i += 512) accum[i] = 0;
            __syncthreads();

            int beg = b * CAP;
            int cnt = cursor[b]; if (cnt > CAP) cnt = CAP;
            int total = cnt * 2;

            int i0 = tid, i1 = tid + 512;
            int2 e0, e1; uint4 q0;
            if (i0 < total) e0 = slab[beg + (i0 >> 1)];
            if (i1 < total) e1 = slab[beg + (i1 >> 1)];
            if (i0 < total) q0 = hq[(size_t)(e0.x & 0xFFFFF) * 2 + (i0 & 1)];

            while (i0 < total) {
                uint4 q1;
                if (i1 < total) q1 = hq[(size_t)(e1.x & 0xFFFFF) * 2 + (i1 & 1)];
                int i2 = i1 + 512;
                int2 e2;
                if (i2 < total) e2 = slab[beg + (i2 >> 1)];

                int p  = i0 & 1;
                int dl = (e0.x >> 20) & (BNODES - 1);
                float wsc = __int_as_float(e0.y) * SCALE1;
                int* a = &accum[dl * APAD + p * 8];
                atomicAdd(a + 0, __float2int_rn(wsc * bf_lo(q0.x)));
                atomicAdd(a + 1, __float2int_rn(wsc * bf_hi(q0.x)));
                atomicAdd(a + 2, __float2int_rn(wsc * bf_lo(q0.y)));
                atomicAdd(a + 3, __float2int_rn(wsc * bf_hi(q0.y)));
                atomicAdd(a + 4, __float2int_rn(wsc * bf_lo(q0.z)));
                atomicAdd(a + 5, __float2int_rn(wsc * bf_hi(q0.z)));
                atomicAdd(a + 6, __float2int_rn(wsc * bf_lo(q0.w)));
                atomicAdd(a + 7, __float2int_rn(wsc * bf_hi(q0.w)));

                e0 = e1; e1 = e2; q0 = q1; i0 = i1; i1 = i2;
            }
            __syncthreads();

            const float inv = 1.0f / SCALE1;
            if (tid < BNODES * 2) {
                int dl = tid >> 1, p = tid & 1;
                int node = (b << BSHIFT) + dl;
                if (node < n) {
                    uint4 qs = hq[(size_t)node * 2 + p];
                    const int* a = &accum[dl * APAD + p * 8];
                    uint4 o;
                    o.x = bf16_rne((float)a[0] * inv + bf_lo(qs.x)) |
                          (bf16_rne((float)a[1] * inv + bf_hi(qs.x)) << 16);
                    o.y = bf16_rne((float)a[2] * inv + bf_lo(qs.y)) |
                          (bf16_rne((float)a[3] * inv + bf_hi(qs.y)) << 16);
                    o.z = bf16_rne((float)a[4] * inv + bf_lo(qs.z)) |
                          (bf16_rne((float)a[5] * inv + bf_hi(qs.z)) << 16);
                    o.w = bf16_rne((float)a[6] * inv + bf_lo(qs.w)) |
                          (bf16_rne((float)a[7] * inv + bf_hi(qs.w)) << 16);
                    outb[(size_t)node * 2 + p] = o;
                }
            }
            __syncthreads();                 // protect accum before next bucket
        }
    }
    grid.sync();

    // ---------------- phase 3: gather layer 2 + W2 + log_softmax ----------------
    {
        const uint4* hq = (const uint4*)h2b;
        for (int i = tid; i < HID * NCLS; i += 512) w2s[i] = W2[i];
        for (int b = bid; b < nbuck; b += G) {
            for (int i = tid; i < BNODES * APAD; i += 512) accum[i] = 0;
            __syncthreads();                 // also fences w2s on first iteration

            int beg = b * CAP;
            int cnt = cursor[b]; if (cnt > CAP) cnt = CAP;
            int node0 = b << BSHIFT;
            int total = cnt * 2;

            int i0 = tid, i1 = tid + 512;
            int2 e0, e1; uint4 q0;
            if (i0 < total) e0 = slab[beg + (i0 >> 1)];
            if (i1 < total) e1 = slab[beg + (i1 >> 1)];
            if (i0 < total) q0 = hq[(size_t)(e0.x & 0xFFFFF) * 2 + (i0 & 1)];

            while (i0 < total) {
                uint4 q1;
                if (i1 < total) q1 = hq[(size_t)(e1.x & 0xFFFFF) * 2 + (i1 & 1)];
                int i2 = i1 + 512;
                int2 e2;
                if (i2 < total) e2 = slab[beg + (i2 >> 1)];

                int p  = i0 & 1;
                int dl = (e0.x >> 20) & (BNODES - 1);
                float wsc = __int_as_float(e0.y) * SCALE2;
                int* a = &accum[dl * APAD + p * 8];
                atomicAdd(a + 0, __float2int_rn(wsc * bf_lo(q0.x)));
                atomicAdd(a + 1, __float2int_rn(wsc * bf_hi(q0.x)));
                atomicAdd(a + 2, __float2int_rn(wsc * bf_lo(q0.y)));
                atomicAdd(a + 3, __float2int_rn(wsc * bf_hi(q0.y)));
                atomicAdd(a + 4, __float2int_rn(wsc * bf_lo(q0.z)));
                atomicAdd(a + 5, __float2int_rn(wsc * bf_hi(q0.z)));
                atomicAdd(a + 6, __float2int_rn(wsc * bf_lo(q0.w)));
                atomicAdd(a + 7, __float2int_rn(wsc * bf_hi(q0.w)));

                e0 = e1; e1 = e2; q0 = q1; i0 = i1; i1 = i2;
            }
            __syncthreads();

            const float inv = 1.0f / SCALE2;
            if (tid < BNODES) {
                int dl = tid;
                int node = node0 + dl;
                if (node < n) {
                    uint4 qa = hq[(size_t)node * 2 + 0];
                    uint4 qb = hq[(size_t)node * 2 + 1];
                    float r[HID];
                    const int* a = &accum[dl * APAD];
                    r[0]  = (float)a[ 0] * inv + bf_lo(qa.x);
                    r[1]  = (float)a[ 1] * inv + bf_hi(qa.x);
                    r[2]  = (float)a[ 2] * inv + bf_lo(qa.y);
                    r[3]  = (float)a[ 3] * inv + bf_hi(qa.y);
                    r[4]  = (float)a[ 4] * inv + bf_lo(qa.z);
                    r[5]  = (float)a[ 5] * inv + bf_hi(qa.z);
                    r[6]  = (float)a[ 6] * inv + bf_lo(qa.w);
                    r[7]  = (float)a[ 7] * inv + bf_hi(qa.w);
                    r[8]  = (float)a[ 8] * inv + bf_lo(qb.x);
                    r[9]  = (float)a[ 9] * inv + bf_hi(qb.x);
                    r[10] = (float)a[10] * inv + bf_lo(qb.y);
                    r[11] = (float)a[11] * inv + bf_hi(qb.y);
                    r[12] = (float)a[12] * inv + bf_lo(qb.z);
                    r[13] = (float)a[13] * inv + bf_hi(qb.z);
                    r[14] = (float)a[14] * inv + bf_lo(qb.w);
                    r[15] = (float)a[15] * inv + bf_hi(qb.w);

                    float z[NCLS];
                    #pragma unroll
                    for (int j = 0; j < NCLS; ++j) z[j] = 0.f;
                    #pragma unroll
                    for (int f = 0; f < HID; ++f) {
                        float rf = r[f];
                        #pragma unroll
                        for (int j = 0; j < NCLS; ++j)
                            z[j] += rf * w2s[f * NCLS + j];
                    }
                    float m = z[0];
                    #pragma unroll
                    for (int j = 1; j < NCLS; ++j) m = fmaxf(m, z[j]);
                    float ssum = 0.f;
                    #pragma unroll
                    for (int j = 0; j < NCLS; ++j) ssum += __expf(z[j] - m);
                    float l = m + __logf(ssum);
                    #pragma unroll
                    for (int j = 0; j < NCLS; ++j) zbuf[dl * ZPAD + j] = z[j] - l;
                }
            }
            __syncthreads();

            for (int i = tid; i < BNODES * NCLS; i += 512) {
                int nl = i / NCLS, j = i - nl * NCLS;
                if (node0 + nl < n)
                    out[(size_t)node0 * NCLS + i] = zbuf[nl * ZPAD + j];
            }
            __syncthreads();                 // protect accum/zbuf before next bucket
        }
    }
}

// ====================== fallback path (proven round-3/4 kernels) ==============

__global__ __launch_bounds__(256) void zero_kernel(int* __restrict__ p, int m)
{
    int i = blockIdx.x * 256 + threadIdx.x;
    if (i < m) p[i] = 0;
}

__global__ __launch_bounds__(256) void bin_gemm_kernel(const int* __restrict__ src,
                                                       const int* __restrict__ dst,
                                                       const float* __restrict__ ew,
                                                       int* __restrict__ cursor,
                                                       int2* __restrict__ slab,
                                                       int E, int nbuck, int nbin,
                                                       const float* __restrict__ x,
                                                       const float* __restrict__ W1,
                                                       unsigned short* __restrict__ h1b,
                                                       int n)
{
    __shared__ int hist[NBUCK_MAX];
    __shared__ int runbase[NBUCK_MAX];
    int tid = threadIdx.x;

    if (blockIdx.x < nbin) {
        for (int i = tid; i < NBUCK_MAX; i += 256) hist[i] = 0;
        __syncthreads();

        int base = blockIdx.x * BIN_CHUNK;
        int myd[16], mys[16], myw[16];
        #pragma unroll
        for (int k = 0; k < 16; ++k) {
            int e = base + k * 256 + tid;
            if (e < E) {
                myd[k] = dst[e];
                mys[k] = src[e];
                myw[k] = __float_as_int(ew[e]);
                atomicAdd(&hist[myd[k] >> BSHIFT], 1);
            } else myd[k] = -1;
        }
        __syncthreads();
        for (int i = tid; i < nbuck; i += 256) {
            int c = hist[i];
            runbase[i] = c ? (i * CAP + atomicAdd(&cursor[i], c)) : 0;
            hist[i] = 0;
        }
        __syncthreads();
        #pragma unroll
        for (int k = 0; k < 16; ++k) {
            int d = myd[k];
            if (d >= 0) {
                int b = d >> BSHIFT;
                int pos = runbase[b] + atomicAdd(&hist[b], 1);
                if (pos < (b + 1) * CAP)
                    slab[pos] = make_int2(mys[k] | ((d & (BNODES - 1)) << 20), myw[k]);
            }
        }
    } else {
        int wave = tid >> 6, lane = tid & 63;
        int m = lane & 15, q = lane >> 4;
        int base = (blockIdx.x - nbin) * 64 + wave * 16;

        short8 bfrag[4];
        #pragma unroll
        for (int kc = 0; kc < 4; ++kc) {
            #pragma unroll
            for (int j = 0; j < 8; ++j)
                bfrag[kc][j] = (short)bf16_rne(W1[(kc * 32 + q * 8 + j) * HID + m]);
        }

        int rowa = base + m; if (rowa > n - 1) rowa = n - 1;
        const float* xr = x + (size_t)rowa * NFEAT;
        f32x4 acc = {0.f, 0.f, 0.f, 0.f};
        #pragma unroll
        for (int kc = 0; kc < 4; ++kc) {
            float4 a0 = *(const float4*)(xr + kc * 32 + q * 8);
            float4 a1 = *(const float4*)(xr + kc * 32 + q * 8 + 4);
            short8 af;
            af[0] = (short)bf16_rne(a0.x); af[1] = (short)bf16_rne(a0.y);
            af[2] = (short)bf16_rne(a0.z); af[3] = (short)bf16_rne(a0.w);
            af[4] = (short)bf16_rne(a1.x); af[5] = (short)bf16_rne(a1.y);
            af[6] = (short)bf16_rne(a1.z); af[7] = (short)bf16_rne(a1.w);
            acc = __builtin_amdgcn_mfma_f32_16x16x32_bf16(af, bfrag[kc], acc, 0, 0, 0);
        }
        #pragma unroll
        for (int reg = 0; reg < 4; ++reg) {
            int rowd = base + q * 4 + reg;
            if (rowd < n)
                h1b[(size_t)rowd * HID + m] = (unsigned short)bf16_rne(acc[reg]);
        }
    }
}

__global__ __launch_bounds__(512) void gather1_kernel(const uint4* __restrict__ hq,
                                                      const int* __restrict__ cursor,
                                                      const int2* __restrict__ slab,
                                                      uint4* __restrict__ outb, int n)
{
    __shared__ int accum[BNODES * APAD];
    int tid = threadIdx.x;
    #pragma unroll
    for (int i = tid; i < BNODES * APAD; i += 512) accum[i] = 0;
    __syncthreads();

    int b = blockIdx.x;
    int beg = b * CAP;
    int cnt = cursor[b]; if (cnt > CAP) cnt = CAP;
    int total = cnt * 2;

    int i0 = tid, i1 = tid + 512;
    int2 e0, e1; uint4 q0;
    if (i0 < total) e0 = slab[beg + (i0 >> 1)];
    if (i1 < total) e1 = slab[beg + (i1 >> 1)];
    if (i0 < total) q0 = hq[(size_t)(e0.x & 0xFFFFF) * 2 + (i0 & 1)];

    while (i0 < total) {
        uint4 q1;
        if (i1 < total) q1 = hq[(size_t)(e1.x & 0xFFFFF) * 2 + (i1 & 1)];
        int i2 = i1 + 512;
        int2 e2;
        if (i2 < total) e2 = slab[beg + (i2 >> 1)];

        int p  = i0 & 1;
        int dl = (e0.x >> 20) & (BNODES - 1);
        float wsc = __int_as_float(e0.y) * SCALE1;
        int* a = &accum[dl * APAD + p * 8];
        atomicAdd(a + 0, __float2int_rn(wsc * bf_lo(q0.x)));
        atomicAdd(a + 1, __float2int_rn(wsc * bf_hi(q0.x)));
        atomicAdd(a + 2, __float2int_rn(wsc * bf_lo(q0.y)));
        atomicAdd(a + 3, __float2int_rn(wsc * bf_hi(q0.y)));
        atomicAdd(a + 4, __float2int_rn(wsc * bf_lo(q0.z)));
        atomicAdd(a + 5, __float2int_rn(wsc * bf_hi(q0.z)));
        atomicAdd(a + 6, __float2int_rn(wsc * bf_lo(q0.w)));
        atomicAdd(a + 7, __float2int_rn(wsc * bf_hi(q0.w)));

        e0 = e1; e1 = e2; q0 = q1; i0 = i1; i1 = i2;
    }
    __syncthreads();

    const float inv = 1.0f / SCALE1;
    if (tid < BNODES * 2) {
        int dl = tid >> 1, p = tid & 1;
        int node = (b << BSHIFT) + dl;
        if (node < n) {
            uint4 qs = hq[(size_t)node * 2 + p];
            const int* a = &accum[dl * APAD + p * 8];
            uint4 o;
            o.x = bf16_rne((float)a[0] * inv + bf_lo(qs.x)) |
                  (bf16_rne((float)a[1] * inv + bf_hi(qs.x)) << 16);
            o.y = bf16_rne((float)a[2] * inv + bf_lo(qs.y)) |
                  (bf16_rne((float)a[3] * inv + bf_hi(qs.y)) << 16);
            o.z = bf16_rne((float)a[4] * inv + bf_lo(qs.z)) |
                  (bf16_rne((float)a[5] * inv + bf_hi(qs.z)) << 16);
            o.w = bf16_rne((float)a[6] * inv + bf_lo(qs.w)) |
                  (bf16_rne((float)a[7] * inv + bf_hi(qs.w)) << 16);
            outb[(size_t)node * 2 + p] = o;
        }
    }
}

__global__ __launch_bounds__(512) void gather2_lsm_kernel(const uint4* __restrict__ hq,
                                                          const int* __restrict__ cursor,
                                                          const int2* __restrict__ slab,
                                                          const float* __restrict__ W2,
                                                          float* __restrict__ out, int n)
{
    __shared__ int   accum[BNODES * APAD];
    __shared__ float w2s[HID * NCLS];
    __shared__ float zbuf[BNODES * ZPAD];
    int tid = threadIdx.x;
    #pragma unroll
    for (int i = tid; i < BNODES * APAD; i += 512) accum[i] = 0;
    for (int i = tid; i < HID * NCLS; i += 512) w2s[i] = W2[i];
    __syncthreads();

    int b = blockIdx.x;
    int beg = b * CAP;
    int cnt = cursor[b]; if (cnt > CAP) cnt = CAP;
    int node0 = b << BSHIFT;
    int total = cnt * 2;

    int i0 = tid, i1 = tid + 512;
    int2 e0, e1; uint4 q0;
    if (i0 < total) e0 = slab[beg + (i0 >> 1)];
    if (i1 < total) e1 = slab[beg + (i1 >> 1)];
    if (i0 < total) q0 = hq[(size_t)(e0.x & 0xFFFFF) * 2 + (i0 & 1)];

    while (i0 < total) {
        uint4 q1;
        if (i1 < total) q1 = hq[(size_t)(e1.x & 0xFFFFF) * 2 + (i1 & 1)];
        int i2 = i1 + 512;
        int2 e2;
        if (i2 < total) e2 = slab[beg + (i2 >> 1)];

        int p  = i0 & 1;
        int dl = (e0.x >> 20) & (BNODES - 1);
        float wsc = __int_as_float(e0.y) * SCALE2;
        int* a = &accum[dl * APAD + p * 8];
        atomicAdd(a + 0, __float2int_rn(wsc * bf_lo(q0.x)));
        atomicAdd(a + 1, __float2int_rn(wsc * bf_hi(q0.x)));
        atomicAdd(a + 2, __float2int_rn(wsc * bf_lo(q0.y)));
        atomicAdd(a + 3, __float2int_rn(wsc * bf_hi(q0.y)));
        atomicAdd(a + 4, __float2int_rn(wsc * bf_lo(q0.z)));
        atomicAdd(a + 5, __float2int_rn(wsc * bf_hi(q0.z)));
        atomicAdd(a + 6, __float2int_rn(wsc * bf_lo(q0.w)));
        atomicAdd(a + 7, __float2int_rn(wsc * bf_hi(q0.w)));

        e0 = e1; e1 = e2; q0 = q1; i0 = i1; i1 = i2;
    }
    __syncthreads();

    const float inv = 1.0f / SCALE2;
    if (tid < BNODES) {
        int dl = tid;
        int node = node0 + dl;
        if (node < n) {
            uint4 qa = hq[(size_t)node * 2 + 0];
            uint4 qb = hq[(size_t)node * 2 + 1];
            float r[HID];
            const int* a = &accum[dl * APAD];
            r[0]  = (float)a[ 0] * inv + bf_lo(qa.x);
            r[1]  = (float)a[ 1] * inv + bf_hi(qa.x);
            r[2]  = (float)a[ 2] * inv + bf_lo(qa.y);
            r[3]  = (float)a[ 3] * inv + bf_hi(qa.y);
            r[4]  = (float)a[ 4] * inv + bf_lo(qa.z);
            r[5]  = (float)a[ 5] * inv + bf_hi(qa.z);
            r[6]  = (float)a[ 6] * inv + bf_lo(qa.w);
            r[7]  = (float)a[ 7] * inv + bf_hi(qa.w);
            r[8]  = (float)a[ 8] * inv + bf_lo(qb.x);
            r[9]  = (float)a[ 9] * inv + bf_hi(qb.x);
            r[10] = (float)a[10] * inv + bf_lo(qb.y);
            r[11] = (float)a[11] * inv + bf_hi(qb.y);
            r[12] = (float)a[12] * inv + bf_lo(qb.z);
            r[13] = (float)a[13] * inv + bf_hi(qb.z);
            r[14] = (float)a[14] * inv + bf_lo(qb.w);
            r[15] = (float)a[15] * inv + bf_hi(qb.w);

            float z[NCLS];
            #pragma unroll
            for (int j = 0; j < NCLS; ++j) z[j] = 0.f;
            #pragma unroll
            for (int f = 0; f < HID; ++f) {
                float rf = r[f];
                #pragma unroll
                for (int j = 0; j < NCLS; ++j)
                    z[j] += rf * w2s[f * NCLS + j];
            }
            float m = z[0];
            #pragma unroll
            for (int j = 1; j < NCLS; ++j) m = fmaxf(m, z[j]);
            float ssum = 0.f;
            #pragma unroll
            for (int j = 0; j < NCLS; ++j) ssum += __expf(z[j] - m);
            float l = m + __logf(ssum);
            #pragma unroll
            for (int j = 0; j < NCLS; ++j) zbuf[dl * ZPAD + j] = z[j] - l;
        }
    }
    __syncthreads();

    for (int i = tid; i < BNODES * NCLS; i += 512) {
        int nl = i / NCLS, j = i - nl * NCLS;
        if (node0 + nl < n)
            out[(size_t)node0 * NCLS + i] = zbuf[nl * ZPAD + j];
    }
}

extern "C" void kernel_launch(void* const* d_in, const int* in_sizes, int n_in,
                              void* d_out, int out_size, void* d_ws, size_t ws_size,
                              hipStream_t stream)
{
    const float* x  = (const float*)d_in[0];
    const float* ew = (const float*)d_in[1];
    const float* W1 = (const float*)d_in[2];
    const float* W2 = (const float*)d_in[3];
    const int*   ei = (const int*)d_in[4];

    int n = in_sizes[0] / NFEAT;     // 100000
    int E = in_sizes[1];             // 1600000
    const int* src = ei;
    const int* dst = ei + E;
    float* out = (float*)d_out;

    int nbuck = (n + BNODES - 1) >> BSHIFT;           // 782
    int nbin  = (E + BIN_CHUNK - 1) / BIN_CHUNK;      // 391

    // ---- workspace layout ----
    char* w = (char*)d_ws;
    int*  cursor = (int*)w;  w += NBUCK_MAX * 4;
    w = (char*)(((size_t)w + 15) & ~(size_t)15);
    int2* slab   = (int2*)w; w += (size_t)NBUCK_MAX * CAP * 8;           // 16 MB
    unsigned short* h1b = (unsigned short*)w; w += (size_t)n * HID * 2;  // 3.2 MB bf16
    unsigned short* h2b = (unsigned short*)w; w += (size_t)n * HID * 2;  // 3.2 MB bf16

    // ---- preferred path: single cooperative dispatch (no inter-kernel boundaries)
    void* kargs[] = {
        (void*)&src, (void*)&dst, (void*)&ew, (void*)&cursor, (void*)&slab,
        (void*)&E, (void*)&nbuck, (void*)&nbin, (void*)&x, (void*)&W1,
        (void*)&h1b, (void*)&h2b, (void*)&W2, (void*)&out, (void*)&n
    };
    hipError_t err = hipLaunchCooperativeKernel((void*)mega_kernel, dim3(256),
                                                dim3(512), kargs, 0, stream);
    if (err != hipSuccess) {
        // ---- fallback: proven 4-dispatch path (round-4 experiment) ----
        int ngemm64 = (n + 63) / 64;
        zero_kernel<<<(NBUCK_MAX + 255) / 256, 256, 0, stream>>>(cursor, NBUCK_MAX);
        bin_gemm_kernel<<<nbin + ngemm64, 256, 0, stream>>>(src, dst, ew, cursor, slab,
                                                            E, nbuck, nbin, x, W1, h1b, n);
        gather1_kernel<<<nbuck, 512, 0, stream>>>((const uint4*)h1b, cursor, slab,
                                                  (uint4*)h2b, n);
        gather2_lsm_kernel<<<nbuck, 512, 0, stream>>>((const uint4*)h2b, cursor, slab,
                                                      W2, out, n);
    }
}

// Round 11
// 168.987 us; speedup vs baseline: 1.5862x; 1.5862x over previous
//
#include <hip/hip_runtime.h>

#define NFEAT 128
#define HID 16
#define NCLS 40
#define BSHIFT 7                 // 128 nodes per bucket
#define BNODES 128
#define CAP 2560                 // slab capacity per bucket (Poisson mean ~2046, 11 sigma)
#define NBUCK_MAX 800            // >= ceil(100000/128)=782
#define BIN_CHUNK 4096           // edges per bin block (16 per thread)
#define APAD 17                  // accum stride: lane's 8 atomics -> 8 distinct banks
#define ZPAD 41

#define SCALE1 262144.0f         // 2^18 — layer-1 message quantization
#define SCALE2 65536.0f          // 2^16 — layer-2 message quantization

typedef __attribute__((ext_vector_type(8))) short short8;   // 8 x bf16 (4 VGPRs)
typedef __attribute__((ext_vector_type(4))) float f32x4;

__device__ __forceinline__ unsigned bf16_rne(float f) {
    unsigned u = __float_as_uint(f);
    return (u + 0x7FFFu + ((u >> 16) & 1u)) >> 16;
}
__device__ __forceinline__ float bf_lo(unsigned u) { return __uint_as_float(u << 16); }
__device__ __forceinline__ float bf_hi(unsigned u) { return __uint_as_float(u & 0xFFFF0000u); }

// ---------- cursor init ----------
__global__ __launch_bounds__(256) void zero_kernel(int* __restrict__ p, int m)
{
    int i = blockIdx.x * 256 + threadIdx.x;
    if (i < m) p[i] = 0;
}

// ---------- fused bin + gemm1 (round-4 structure; boundaries proven cheap but
// the fusion still overlaps bin's latency-stalls with gemm's BW work) ----------
__global__ __launch_bounds__(256) void bin_gemm_kernel(const int* __restrict__ src,
                                                       const int* __restrict__ dst,
                                                       const float* __restrict__ ew,
                                                       int* __restrict__ cursor,
                                                       int2* __restrict__ slab,
                                                       int E, int nbuck, int nbin,
                                                       const float* __restrict__ x,
                                                       const float* __restrict__ W1,
                                                       unsigned short* __restrict__ h1b,
                                                       int n)
{
    __shared__ int hist[NBUCK_MAX];      // 3.2 KB (bin path only)
    __shared__ int runbase[NBUCK_MAX];   // 3.2 KB (bin path only)
    int tid = threadIdx.x;

    if (blockIdx.x < nbin) {
        // ================= bin path =================
        for (int i = tid; i < NBUCK_MAX; i += 256) hist[i] = 0;
        __syncthreads();

        int base = blockIdx.x * BIN_CHUNK;
        int myd[16], mys[16], myw[16];
        #pragma unroll
        for (int k = 0; k < 16; ++k) {
            int e = base + k * 256 + tid;
            if (e < E) {
                myd[k] = dst[e];
                mys[k] = src[e];
                myw[k] = __float_as_int(ew[e]);
                atomicAdd(&hist[myd[k] >> BSHIFT], 1);       // native ds_add
            } else myd[k] = -1;
        }
        __syncthreads();
        for (int i = tid; i < nbuck; i += 256) {
            int c = hist[i];
            runbase[i] = c ? (i * CAP + atomicAdd(&cursor[i], c)) : 0;
            hist[i] = 0;                                     // reuse as intra-block cursor
        }
        __syncthreads();
        #pragma unroll
        for (int k = 0; k < 16; ++k) {
            int d = myd[k];
            if (d >= 0) {
                int b = d >> BSHIFT;
                int pos = runbase[b] + atomicAdd(&hist[b], 1);
                if (pos < (b + 1) * CAP)                     // overflow guard
                    slab[pos] = make_int2(mys[k] | ((d & (BNODES - 1)) << 20), myw[k]);
            }
        }
    } else {
        // ================= gemm1 path =================
        int wave = tid >> 6, lane = tid & 63;
        int m = lane & 15, q = lane >> 4;
        int base = (blockIdx.x - nbin) * 64 + wave * 16;

        short8 bfrag[4];
        #pragma unroll
        for (int kc = 0; kc < 4; ++kc) {
            #pragma unroll
            for (int j = 0; j < 8; ++j)
                bfrag[kc][j] = (short)bf16_rne(W1[(kc * 32 + q * 8 + j) * HID + m]);
        }

        int rowa = base + m; if (rowa > n - 1) rowa = n - 1;
        const float* xr = x + (size_t)rowa * NFEAT;
        f32x4 acc = {0.f, 0.f, 0.f, 0.f};
        #pragma unroll
        for (int kc = 0; kc < 4; ++kc) {
            float4 a0 = *(const float4*)(xr + kc * 32 + q * 8);
            float4 a1 = *(const float4*)(xr + kc * 32 + q * 8 + 4);
            short8 af;
            af[0] = (short)bf16_rne(a0.x); af[1] = (short)bf16_rne(a0.y);
            af[2] = (short)bf16_rne(a0.z); af[3] = (short)bf16_rne(a0.w);
            af[4] = (short)bf16_rne(a1.x); af[5] = (short)bf16_rne(a1.y);
            af[6] = (short)bf16_rne(a1.z); af[7] = (short)bf16_rne(a1.w);
            acc = __builtin_amdgcn_mfma_f32_16x16x32_bf16(af, bfrag[kc], acc, 0, 0, 0);
        }
        #pragma unroll
        for (int reg = 0; reg < 4; ++reg) {
            int rowd = base + q * 4 + reg;
            if (rowd < n)
                h1b[(size_t)rowd * HID + m] = (unsigned short)bf16_rne(acc[reg]);
        }
    }
}

// ---------- gather layer 1: 5-stage pipelined fixed-point LDS accumulation ----
// v2: edges prefetched 4 ahead, hq gathers 3 ahead (use-distance = 3 iters,
// 3-4 outstanding loads/wave) — mega_kernel counters showed the 2-stage loop
// was latency-bound (VALUBusy 9.5%, HBM 9.8%, nothing saturated).
// __launch_bounds__(512,8): VGPR<=64 -> 32 waves/CU latency hiding.
__global__ __launch_bounds__(512, 8) void gather1_kernel(const uint4* __restrict__ hq,
                                                         const int* __restrict__ cursor,
                                                         const int2* __restrict__ slab,
                                                         uint4* __restrict__ outb, int n)
{
    __shared__ int accum[BNODES * APAD];   // 8.7 KB, [dl][f] pad-17
    int tid = threadIdx.x;
    #pragma unroll
    for (int i = tid; i < BNODES * APAD; i += 512) accum[i] = 0;
    __syncthreads();

    int b = blockIdx.x;
    int beg = b * CAP;
    int cnt = cursor[b]; if (cnt > CAP) cnt = CAP;
    int total = cnt * 2;                  // 2 lanes per edge, 8 feats each

    int i0 = tid, i1 = tid + 512, i2 = tid + 1024, i3 = tid + 1536;
    int2 e0, e1, e2, e3; uint4 q0, q1, q2;
    if (i0 < total) e0 = slab[beg + (i0 >> 1)];
    if (i1 < total) e1 = slab[beg + (i1 >> 1)];
    if (i2 < total) e2 = slab[beg + (i2 >> 1)];
    if (i3 < total) e3 = slab[beg + (i3 >> 1)];
    if (i0 < total) q0 = hq[(size_t)(e0.x & 0xFFFFF) * 2 + (i0 & 1)];
    if (i1 < total) q1 = hq[(size_t)(e1.x & 0xFFFFF) * 2 + (i1 & 1)];
    if (i2 < total) q2 = hq[(size_t)(e2.x & 0xFFFFF) * 2 + (i2 & 1)];

    while (i0 < total) {
        uint4 q3;
        if (i3 < total) q3 = hq[(size_t)(e3.x & 0xFFFFF) * 2 + (i3 & 1)];
        int i4 = i3 + 512;
        int2 e4;
        if (i4 < total) e4 = slab[beg + (i4 >> 1)];

        int p  = i0 & 1;
        int dl = (e0.x >> 20) & (BNODES - 1);
        float wsc = __int_as_float(e0.y) * SCALE1;
        int* a = &accum[dl * APAD + p * 8];
        atomicAdd(a + 0, __float2int_rn(wsc * bf_lo(q0.x)));
        atomicAdd(a + 1, __float2int_rn(wsc * bf_hi(q0.x)));
        atomicAdd(a + 2, __float2int_rn(wsc * bf_lo(q0.y)));
        atomicAdd(a + 3, __float2int_rn(wsc * bf_hi(q0.y)));
        atomicAdd(a + 4, __float2int_rn(wsc * bf_lo(q0.z)));
        atomicAdd(a + 5, __float2int_rn(wsc * bf_hi(q0.z)));
        atomicAdd(a + 6, __float2int_rn(wsc * bf_lo(q0.w)));
        atomicAdd(a + 7, __float2int_rn(wsc * bf_hi(q0.w)));

        e0 = e1; e1 = e2; e2 = e3; e3 = e4;
        q0 = q1; q1 = q2; q2 = q3;
        i0 = i1; i1 = i2; i2 = i3; i3 = i4;
    }
    __syncthreads();

    const float inv = 1.0f / SCALE1;
    if (tid < BNODES * 2) {
        int dl = tid >> 1, p = tid & 1;
        int node = (b << BSHIFT) + dl;
        if (node < n) {
            uint4 qs = hq[(size_t)node * 2 + p];
            const int* a = &accum[dl * APAD + p * 8];
            uint4 o;
            o.x = bf16_rne((float)a[0] * inv + bf_lo(qs.x)) |
                  (bf16_rne((float)a[1] * inv + bf_hi(qs.x)) << 16);
            o.y = bf16_rne((float)a[2] * inv + bf_lo(qs.y)) |
                  (bf16_rne((float)a[3] * inv + bf_hi(qs.y)) << 16);
            o.z = bf16_rne((float)a[4] * inv + bf_lo(qs.z)) |
                  (bf16_rne((float)a[5] * inv + bf_hi(qs.z)) << 16);
            o.w = bf16_rne((float)a[6] * inv + bf_lo(qs.w)) |
                  (bf16_rne((float)a[7] * inv + bf_hi(qs.w)) << 16);
            outb[(size_t)node * 2 + p] = o;
        }
    }
}

// ---------- gather layer 2 + W2 projection + log_softmax, 5-stage pipeline ----
// __launch_bounds__(512,6): VGPR<=85 (z[40] epilogue needs headroom) -> 24 waves/CU.
__global__ __launch_bounds__(512, 6) void gather2_lsm_kernel(const uint4* __restrict__ hq,
                                                             const int* __restrict__ cursor,
                                                             const int2* __restrict__ slab,
                                                             const float* __restrict__ W2,
                                                             float* __restrict__ out, int n)
{
    __shared__ int   accum[BNODES * APAD];  // 8.7 KB
    __shared__ float w2s[HID * NCLS];       // 2.56 KB
    __shared__ float zbuf[BNODES * ZPAD];   // 21 KB
    int tid = threadIdx.x;
    #pragma unroll
    for (int i = tid; i < BNODES * APAD; i += 512) accum[i] = 0;
    for (int i = tid; i < HID * NCLS; i += 512) w2s[i] = W2[i];
    __syncthreads();

    int b = blockIdx.x;
    int beg = b * CAP;
    int cnt = cursor[b]; if (cnt > CAP) cnt = CAP;
    int node0 = b << BSHIFT;
    int total = cnt * 2;

    int i0 = tid, i1 = tid + 512, i2 = tid + 1024, i3 = tid + 1536;
    int2 e0, e1, e2, e3; uint4 q0, q1, q2;
    if (i0 < total) e0 = slab[beg + (i0 >> 1)];
    if (i1 < total) e1 = slab[beg + (i1 >> 1)];
    if (i2 < total) e2 = slab[beg + (i2 >> 1)];
    if (i3 < total) e3 = slab[beg + (i3 >> 1)];
    if (i0 < total) q0 = hq[(size_t)(e0.x & 0xFFFFF) * 2 + (i0 & 1)];
    if (i1 < total) q1 = hq[(size_t)(e1.x & 0xFFFFF) * 2 + (i1 & 1)];
    if (i2 < total) q2 = hq[(size_t)(e2.x & 0xFFFFF) * 2 + (i2 & 1)];

    while (i0 < total) {
        uint4 q3;
        if (i3 < total) q3 = hq[(size_t)(e3.x & 0xFFFFF) * 2 + (i3 & 1)];
        int i4 = i3 + 512;
        int2 e4;
        if (i4 < total) e4 = slab[beg + (i4 >> 1)];

        int p  = i0 & 1;
        int dl = (e0.x >> 20) & (BNODES - 1);
        float wsc = __int_as_float(e0.y) * SCALE2;
        int* a = &accum[dl * APAD + p * 8];
        atomicAdd(a + 0, __float2int_rn(wsc * bf_lo(q0.x)));
        atomicAdd(a + 1, __float2int_rn(wsc * bf_hi(q0.x)));
        atomicAdd(a + 2, __float2int_rn(wsc * bf_lo(q0.y)));
        atomicAdd(a + 3, __float2int_rn(wsc * bf_hi(q0.y)));
        atomicAdd(a + 4, __float2int_rn(wsc * bf_lo(q0.z)));
        atomicAdd(a + 5, __float2int_rn(wsc * bf_hi(q0.z)));
        atomicAdd(a + 6, __float2int_rn(wsc * bf_lo(q0.w)));
        atomicAdd(a + 7, __float2int_rn(wsc * bf_hi(q0.w)));

        e0 = e1; e1 = e2; e2 = e3; e3 = e4;
        q0 = q1; q1 = q2; q2 = q3;
        i0 = i1; i1 = i2; i2 = i3; i3 = i4;
    }
    __syncthreads();

    const float inv = 1.0f / SCALE2;
    if (tid < BNODES) {
        int dl = tid;
        int node = node0 + dl;
        if (node < n) {
            uint4 qa = hq[(size_t)node * 2 + 0];
            uint4 qb = hq[(size_t)node * 2 + 1];
            float r[HID];
            const int* a = &accum[dl * APAD];
            r[0]  = (float)a[ 0] * inv + bf_lo(qa.x);
            r[1]  = (float)a[ 1] * inv + bf_hi(qa.x);
            r[2]  = (float)a[ 2] * inv + bf_lo(qa.y);
            r[3]  = (float)a[ 3] * inv + bf_hi(qa.y);
            r[4]  = (float)a[ 4] * inv + bf_lo(qa.z);
            r[5]  = (float)a[ 5] * inv + bf_hi(qa.z);
            r[6]  = (float)a[ 6] * inv + bf_lo(qa.w);
            r[7]  = (float)a[ 7] * inv + bf_hi(qa.w);
            r[8]  = (float)a[ 8] * inv + bf_lo(qb.x);
            r[9]  = (float)a[ 9] * inv + bf_hi(qb.x);
            r[10] = (float)a[10] * inv + bf_lo(qb.y);
            r[11] = (float)a[11] * inv + bf_hi(qb.y);
            r[12] = (float)a[12] * inv + bf_lo(qb.z);
            r[13] = (float)a[13] * inv + bf_hi(qb.z);
            r[14] = (float)a[14] * inv + bf_lo(qb.w);
            r[15] = (float)a[15] * inv + bf_hi(qb.w);

            float z[NCLS];
            #pragma unroll
            for (int j = 0; j < NCLS; ++j) z[j] = 0.f;
            #pragma unroll
            for (int f = 0; f < HID; ++f) {
                float rf = r[f];
                #pragma unroll
                for (int j = 0; j < NCLS; ++j)
                    z[j] += rf * w2s[f * NCLS + j];   // broadcast reads
            }
            float m = z[0];
            #pragma unroll
            for (int j = 1; j < NCLS; ++j) m = fmaxf(m, z[j]);
            float ssum = 0.f;
            #pragma unroll
            for (int j = 0; j < NCLS; ++j) ssum += __expf(z[j] - m);
            float l = m + __logf(ssum);
            #pragma unroll
            for (int j = 0; j < NCLS; ++j) zbuf[dl * ZPAD + j] = z[j] - l;
        }
    }
    __syncthreads();

    for (int i = tid; i < BNODES * NCLS; i += 512) {
        int nl = i / NCLS, j = i - nl * NCLS;
        if (node0 + nl < n)
            out[(size_t)node0 * NCLS + i] = zbuf[nl * ZPAD + j];
    }
}

extern "C" void kernel_launch(void* const* d_in, const int* in_sizes, int n_in,
                              void* d_out, int out_size, void* d_ws, size_t ws_size,
                              hipStream_t stream)
{
    const float* x  = (const float*)d_in[0];
    const float* ew = (const float*)d_in[1];
    const float* W1 = (const float*)d_in[2];
    const float* W2 = (const float*)d_in[3];
    const int*   ei = (const int*)d_in[4];

    int n = in_sizes[0] / NFEAT;     // 100000
    int E = in_sizes[1];             // 1600000
    const int* src = ei;
    const int* dst = ei + E;
    float* out = (float*)d_out;

    int nbuck = (n + BNODES - 1) >> BSHIFT;           // 782
    int nbin  = (E + BIN_CHUNK - 1) / BIN_CHUNK;      // 391
    int ngemm = (n + 63) / 64;                        // 1563

    // ---- workspace layout ----
    char* w = (char*)d_ws;
    int*  cursor = (int*)w;  w += NBUCK_MAX * 4;
    w = (char*)(((size_t)w + 15) & ~(size_t)15);
    int2* slab   = (int2*)w; w += (size_t)NBUCK_MAX * CAP * 8;           // 16 MB
    unsigned short* h1b = (unsigned short*)w; w += (size_t)n * HID * 2;  // 3.2 MB bf16
    unsigned short* h2b = (unsigned short*)w; w += (size_t)n * HID * 2;  // 3.2 MB bf16

    zero_kernel<<<(NBUCK_MAX + 255) / 256, 256, 0, stream>>>(cursor, NBUCK_MAX);
    bin_gemm_kernel<<<nbin + ngemm, 256, 0, stream>>>(src, dst, ew, cursor, slab,
                                                      E, nbuck, nbin, x, W1, h1b, n);
    gather1_kernel<<<nbuck, 512, 0, stream>>>((const uint4*)h1b, cursor, slab,
                                              (uint4*)h2b, n);
    gather2_lsm_kernel<<<nbuck, 512, 0, stream>>>((const uint4*)h2b, cursor, slab,
                                                  W2, out, n);
}